// Round 4
// baseline (2606.268 us; speedup 1.0000x reference)
//
#include <hip/hip_runtime.h>
#include <cstdint>

#define N_NODES 49152
#define DIM 512
#define NH 8
#define DHEAD 64
#define NE 131072
#define ETOT (NE + N_NODES)   /* 180224 */
#define NLAYERS 5

typedef short short8 __attribute__((ext_vector_type(8)));
typedef float floatx4 __attribute__((ext_vector_type(4)));

__device__ __forceinline__ float bf2f(unsigned short v) {
  union { unsigned int u; float f; } x; x.u = ((unsigned int)v) << 16; return x.f;
}
__device__ __forceinline__ unsigned short f2bf(float f) {
  union { float f; unsigned int u; } x; x.f = f;
  unsigned int r = x.u + 0x7fffu + ((x.u >> 16) & 1u);
  return (unsigned short)(r >> 16);
}
__device__ __forceinline__ void async_load16(const void* g, void* l) {
  __builtin_amdgcn_global_load_lds((const __attribute__((address_space(1))) void*)g,
                                   (__attribute__((address_space(3))) void*)l, 16, 0, 0);
}

// ---------------- x: fp32 -> bf16 ----------------
__global__ __launch_bounds__(256) void convert_x_r4(const float* __restrict__ xf, unsigned short* __restrict__ xb)
{
  const size_t i = ((size_t)blockIdx.x * 256 + threadIdx.x) * 8;
  const float4 a = *(const float4*)&xf[i];
  const float4 b = *(const float4*)&xf[i + 4];
  unsigned int ov[4];
  ov[0] = (unsigned int)f2bf(a.x) | ((unsigned int)f2bf(a.y) << 16);
  ov[1] = (unsigned int)f2bf(a.z) | ((unsigned int)f2bf(a.w) << 16);
  ov[2] = (unsigned int)f2bf(b.x) | ((unsigned int)f2bf(b.y) << 16);
  ov[3] = (unsigned int)f2bf(b.z) | ((unsigned int)f2bf(b.w) << 16);
  *(uint4*)&xb[i] = *(const uint4*)ov;
}

// ---------------- W transpose + convert: WT[l][n][k] = bf16(Ws[l][k][n]) ----------------
__global__ void transpose_w_r4(const float* __restrict__ Ws, unsigned short* __restrict__ WT)
{
  __shared__ float tile[32][33];
  const int l  = blockIdx.z;
  const int nt = blockIdx.x * 32, kt = blockIdx.y * 32;
  const int tx = threadIdx.x & 31, ty = threadIdx.x >> 5;   // 256 threads
  #pragma unroll
  for (int r = 0; r < 32; r += 8)
    tile[ty + r][tx] = Ws[(size_t)l*DIM*DIM + (size_t)(kt + ty + r)*DIM + nt + tx];
  __syncthreads();
  #pragma unroll
  for (int r = 0; r < 32; r += 8)
    WT[(size_t)l*DIM*DIM + (size_t)(nt + ty + r)*DIM + kt + tx] = f2bf(tile[tx][ty + r]);
}

// ---------------- edge index canonicalize (auto-detect int64 vs int32) ----------------
__global__ void repack_edges_r4(const int* __restrict__ raw, int* __restrict__ eidx)
{
  const int i = blockIdx.x * 256 + threadIdx.x;    // 2*NE threads
  bool is64 = true;
  #pragma unroll
  for (int j = 0; j < 16; j++) is64 = is64 && (raw[2*j + 1] == 0);
  int v;
  if (is64) v = (int)((const long long*)raw)[i];
  else      v = raw[i];
  eidx[i] = v;
}

// ---------------- CSR build ----------------
__global__ void init_counts_r4(int* __restrict__ counts) {
  counts[blockIdx.x * 256 + threadIdx.x] = 1;    // self-loop
}
__global__ void hist_dst_r4(const int* __restrict__ eidx, int* __restrict__ counts) {
  const int i = blockIdx.x * 256 + threadIdx.x;  // NE threads
  atomicAdd(&counts[eidx[NE + i]], 1);
}
__global__ void scan_kernel_r4(const int* __restrict__ counts, int* __restrict__ offs, int* __restrict__ cursor)
{
  __shared__ int tot[1024];
  const int t = threadIdx.x;
  const int base = t * 48;                       // N_NODES = 1024*48
  int s = 0;
  for (int i = 0; i < 48; i++) s += counts[base + i];
  tot[t] = s;
  __syncthreads();
  for (int o = 1; o < 1024; o <<= 1) {
    int v = (t >= o) ? tot[t - o] : 0;
    __syncthreads();
    tot[t] += v;
    __syncthreads();
  }
  int run = tot[t] - s;
  for (int i = 0; i < 48; i++) {
    offs[base + i] = run;
    cursor[base + i] = run;
    run += counts[base + i];
  }
  if (t == 1023) offs[N_NODES] = tot[1023];
}
__global__ void scatter_edges_r4(const int* __restrict__ eidx, int* __restrict__ cursor, int* __restrict__ csrc)
{
  const int i = blockIdx.x * 256 + threadIdx.x;  // ETOT threads
  int s, d;
  if (i < NE) { s = eidx[i]; d = eidx[NE + i]; }
  else        { s = i - NE; d = s; }
  const int pos = atomicAdd(&cursor[d], 1);
  csrc[pos] = s;
}

// ---------------- GEMM: C = bnrelu(A) @ BT^T (bf16 MFMA, fused BN+ReLU on A) ----------------
// apply_bn=0: A staged async (layer 0). apply_bn=1: A staged sync with y=relu(a*scale+shift).
// B always staged via global_load_lds width=16.
__global__ __launch_bounds__(256) void gemm_bt_r4(const unsigned short* __restrict__ A,
                                                  const unsigned short* __restrict__ BT,
                                                  const float* __restrict__ scale,
                                                  const float* __restrict__ shift,
                                                  const int apply_bn,
                                                  unsigned short* __restrict__ C)
{
  __shared__ unsigned short As[128 * 64];
  __shared__ unsigned short Bs[128 * 64];
  const int m0 = blockIdx.x * 128;
  const int n0 = blockIdx.y * 128;
  const int tid = threadIdx.x;
  const int wv = tid >> 6, lane = tid & 63;
  const int wr = (wv >> 1) * 64, wc = (wv & 1) * 64;
  const int q = lane >> 4, c16 = lane & 15;
  const int arow = lane >> 3;          // 0..7 within an 8-row chunk
  const int acol = (lane & 7) * 8;     // k offset within BK

  floatx4 acc[4][4] = {};

  for (int k0 = 0; k0 < DIM; k0 += 64) {
    // B tile: async (16 chunks of 8 rows x 64 k, 1 KiB each; wave wv stages 4)
    #pragma unroll
    for (int t = 0; t < 4; t++) {
      const int cb = wv * 4 + t;
      async_load16(BT + (size_t)(n0 + cb*8 + arow)*DIM + k0 + acol, &Bs[cb * 512]);
    }
    if (!apply_bn) {
      #pragma unroll
      for (int t = 0; t < 4; t++) {
        const int cb = wv * 4 + t;
        async_load16(A + (size_t)(m0 + cb*8 + arow)*DIM + k0 + acol, &As[cb * 512]);
      }
    } else {
      #pragma unroll
      for (int p = 0; p < 4; p++) {
        const int idx = (p * 256 + tid) * 8;    // element index within 128x64 tile
        const int row = idx >> 6, col = idx & 63;
        const uint4 v = *(const uint4*)&A[(size_t)(m0 + row) * DIM + k0 + col];
        const unsigned int* vp = (const unsigned int*)&v;
        unsigned int ov[4];
        #pragma unroll
        for (int j = 0; j < 4; j++) {
          const int c = k0 + col + 2*j;
          const float a0 = bf2f((unsigned short)(vp[j] & 0xffffu));
          const float a1 = bf2f((unsigned short)(vp[j] >> 16));
          const float y0 = fmaxf(0.f, a0 * scale[c]     + shift[c]);
          const float y1 = fmaxf(0.f, a1 * scale[c + 1] + shift[c + 1]);
          ov[j] = (unsigned int)f2bf(y0) | ((unsigned int)f2bf(y1) << 16);
        }
        *(uint4*)&As[idx] = *(const uint4*)ov;
      }
    }
    __syncthreads();
    #pragma unroll
    for (int kk = 0; kk < 64; kk += 32) {
      short8 aF[4], bF[4];
      #pragma unroll
      for (int mt = 0; mt < 4; mt++)
        aF[mt] = *(const short8*)&As[(wr + mt*16 + c16) * 64 + kk + q*8];
      #pragma unroll
      for (int nt = 0; nt < 4; nt++)
        bF[nt] = *(const short8*)&Bs[(wc + nt*16 + c16) * 64 + kk + q*8];
      #pragma unroll
      for (int mt = 0; mt < 4; mt++)
        #pragma unroll
        for (int nt = 0; nt < 4; nt++)
          acc[mt][nt] = __builtin_amdgcn_mfma_f32_16x16x32_bf16(aF[mt], bF[nt], acc[mt][nt], 0, 0, 0);
    }
    __syncthreads();
  }
  // C/D layout (verified m89/m91): col = lane&15, row = (lane>>4)*4 + reg
  #pragma unroll
  for (int mt = 0; mt < 4; mt++) {
    #pragma unroll
    for (int nt = 0; nt < 4; nt++) {
      const int col = n0 + wc + nt*16 + c16;
      #pragma unroll
      for (int r = 0; r < 4; r++) {
        const int row = m0 + wr + mt*16 + q*4 + r;
        C[(size_t)row * DIM + col] = f2bf(acc[mt][nt][r]);
      }
    }
  }
}

// ---------------- attention logits ----------------
__global__ __launch_bounds__(256) void attn_logits_r4(const unsigned short* __restrict__ Hm,
    const float* __restrict__ asrc, const float* __restrict__ adst,
    float* __restrict__ als, float* __restrict__ ald)
{
  const int wv = threadIdx.x >> 6, lane = threadIdx.x & 63;
  const int node = blockIdx.x * 4 + wv;
  const int hd = lane >> 3;
  const uint4 hv = *(const uint4*)&Hm[(size_t)node * DIM + lane * 8];
  const unsigned int* hp = (const unsigned int*)&hv;
  const float4 sA = ((const float4*)(asrc + (size_t)lane * 8))[0];
  const float4 sB = ((const float4*)(asrc + (size_t)lane * 8))[1];
  const float4 dA = ((const float4*)(adst + (size_t)lane * 8))[0];
  const float4 dB = ((const float4*)(adst + (size_t)lane * 8))[1];
  const float sarr[8] = {sA.x, sA.y, sA.z, sA.w, sB.x, sB.y, sB.z, sB.w};
  const float darr[8] = {dA.x, dA.y, dA.z, dA.w, dB.x, dB.y, dB.z, dB.w};
  float ss = 0.f, sd = 0.f;
  #pragma unroll
  for (int i = 0; i < 4; i++) {
    const float h0 = bf2f((unsigned short)(hp[i] & 0xffffu));
    const float h1 = bf2f((unsigned short)(hp[i] >> 16));
    ss += h0 * sarr[2*i] + h1 * sarr[2*i + 1];
    sd += h0 * darr[2*i] + h1 * darr[2*i + 1];
  }
  #pragma unroll
  for (int msk = 1; msk <= 4; msk <<= 1) {
    ss += __shfl_xor(ss, msk, 64);
    sd += __shfl_xor(sd, msk, 64);
  }
  if ((lane & 7) == 0) {
    als[node * NH + hd] = ss;
    ald[node * NH + hd] = sd;
  }
}

// ---------------- GAT aggregate (softmax over CSR segment) + bias ----------------
__global__ __launch_bounds__(256) void gat_agg_r4(const unsigned short* __restrict__ Hm,
    const float* __restrict__ als, const float* __restrict__ ald,
    const int* __restrict__ offs, const int* __restrict__ csrc,
    const float* __restrict__ bconv, unsigned short* __restrict__ Xout)
{
  const int wv = threadIdx.x >> 6, lane = threadIdx.x & 63;
  const int node = blockIdx.x * 4 + wv;
  const int hd = lane >> 3;
  const float aldv = ald[node * NH + hd];
  const int e0 = offs[node], e1 = offs[node + 1];
  float m = -1e30f, z = 0.f;
  for (int e = e0; e < e1; e++) {
    const int s = csrc[e];
    float lg = als[s * NH + hd] + aldv;
    lg = lg > 0.f ? lg : 0.2f * lg;
    const float mn = fmaxf(m, lg);
    z = z * __expf(m - mn) + __expf(lg - mn);
    m = mn;
  }
  const float zinv = 1.f / (z + 1e-16f);
  float acc[8] = {};
  for (int e = e0; e < e1; e++) {
    const int s = csrc[e];
    float lg = als[s * NH + hd] + aldv;
    lg = lg > 0.f ? lg : 0.2f * lg;
    const float w = __expf(lg - m) * zinv;
    const uint4 hv = *(const uint4*)&Hm[(size_t)s * DIM + lane * 8];
    const unsigned int* hp = (const unsigned int*)&hv;
    #pragma unroll
    for (int j = 0; j < 4; j++) {
      acc[2*j]   += w * bf2f((unsigned short)(hp[j] & 0xffffu));
      acc[2*j+1] += w * bf2f((unsigned short)(hp[j] >> 16));
    }
  }
  const float4 bA = ((const float4*)(bconv + (size_t)lane * 8))[0];
  const float4 bB = ((const float4*)(bconv + (size_t)lane * 8))[1];
  const float barr[8] = {bA.x, bA.y, bA.z, bA.w, bB.x, bB.y, bB.z, bB.w};
  unsigned int ov[4];
  #pragma unroll
  for (int j = 0; j < 4; j++) {
    ov[j] = (unsigned int)f2bf(acc[2*j] + barr[2*j])
          | ((unsigned int)f2bf(acc[2*j+1] + barr[2*j+1]) << 16);
  }
  *(uint4*)&Xout[(size_t)node * DIM + lane * 8] = *(const uint4*)ov;
}

// ---------------- BatchNorm stats (rewritten: 1536 blocks, uint4, LDS reduce) ----------------
__global__ void zero_sums_r4(float* __restrict__ sums) {
  const int t = threadIdx.x;   // 256
  sums[t] = 0.f; sums[256 + t] = 0.f; sums[512 + t] = 0.f; sums[768 + t] = 0.f;
}
__global__ __launch_bounds__(256) void bn_stats_r4(const unsigned short* __restrict__ X, float* __restrict__ sums)
{
  // block b covers rows [b*32, b*32+32). 256 threads = 4 rows x 64 col-groups (8 cols each).
  __shared__ float red[4][64][16];
  const int t = threadIdx.x;
  const int g = t >> 6, cg = t & 63;       // row-group, col-group
  const int c0 = cg * 8;
  const int r0 = blockIdx.x * 32;
  float s[8] = {}, qq[8] = {};
  for (int it = 0; it < 8; it++) {
    const int row = r0 + it * 4 + g;
    const uint4 v = *(const uint4*)&X[(size_t)row * DIM + c0];
    const unsigned int* vp = (const unsigned int*)&v;
    #pragma unroll
    for (int j = 0; j < 4; j++) {
      const float a = bf2f((unsigned short)(vp[j] & 0xffffu));
      const float b = bf2f((unsigned short)(vp[j] >> 16));
      s[2*j] += a;  qq[2*j] += a * a;
      s[2*j+1] += b; qq[2*j+1] += b * b;
    }
  }
  #pragma unroll
  for (int j = 0; j < 8; j++) { red[g][cg][j] = s[j]; red[g][cg][8 + j] = qq[j]; }
  __syncthreads();
  if (g == 0) {
    #pragma unroll
    for (int j = 0; j < 8; j++) {
      const float sv = red[0][cg][j] + red[1][cg][j] + red[2][cg][j] + red[3][cg][j];
      const float qv = red[0][cg][8+j] + red[1][cg][8+j] + red[2][cg][8+j] + red[3][cg][8+j];
      atomicAdd(&sums[c0 + j], sv);
      atomicAdd(&sums[512 + c0 + j], qv);
    }
  }
}
__global__ void bn_finalize_r4(const float* __restrict__ sums, const float* __restrict__ gamma,
                               const float* __restrict__ beta,
                               float* __restrict__ scale, float* __restrict__ shift)
{
  const int c = threadIdx.x;   // 512
  const float inv = 1.0f / (float)N_NODES;
  const float mean = sums[c] * inv;
  float var = sums[512 + c] * inv - mean * mean;
  var = fmaxf(var, 0.f);
  const float rs = rsqrtf(var + 1e-5f);
  const float sc = gamma[c] * rs;
  scale[c] = sc;
  shift[c] = beta[c] - mean * sc;
}

// ---------------- final head: out[n] = relu(bn(X[n,:])) . Wl + bl ----------------
__global__ __launch_bounds__(256) void final_head_r4(const unsigned short* __restrict__ X,
    const float* __restrict__ scale, const float* __restrict__ shift,
    const float* __restrict__ wl, const float* __restrict__ blp,
    float* __restrict__ out)
{
  const int wv = threadIdx.x >> 6, lane = threadIdx.x & 63;
  const int node = blockIdx.x * 4 + wv;
  const uint4 xv = *(const uint4*)&X[(size_t)node * DIM + lane * 8];
  const unsigned int* xp = (const unsigned int*)&xv;
  const int c0 = lane * 8;
  float s = 0.f;
  #pragma unroll
  for (int i = 0; i < 4; i++) {
    const float a0 = bf2f((unsigned short)(xp[i] & 0xffffu));
    const float a1 = bf2f((unsigned short)(xp[i] >> 16));
    const float y0 = fmaxf(0.f, a0 * scale[c0 + 2*i]     + shift[c0 + 2*i]);
    const float y1 = fmaxf(0.f, a1 * scale[c0 + 2*i + 1] + shift[c0 + 2*i + 1]);
    s += y0 * wl[c0 + 2*i] + y1 * wl[c0 + 2*i + 1];
  }
  #pragma unroll
  for (int msk = 32; msk >= 1; msk >>= 1) s += __shfl_xor(s, msk, 64);
  if (lane == 0) out[node] = s + blp[0];
}

extern "C" void kernel_launch(void* const* d_in, const int* in_sizes, int n_in,
                              void* d_out, int out_size, void* d_ws, size_t ws_size,
                              hipStream_t stream)
{
  const float* x_in  = (const float*)d_in[0];
  const int*   ei    = (const int*)d_in[1];
  const float* Ws    = (const float*)d_in[2];
  const float* Asrc  = (const float*)d_in[3];
  const float* Adst  = (const float*)d_in[4];
  const float* Bconv = (const float*)d_in[5];
  const float* Gamma = (const float*)d_in[6];
  const float* Beta  = (const float*)d_in[7];
  const float* Wl    = (const float*)d_in[8];
  const float* bl    = (const float*)d_in[9];
  float* out = (float*)d_out;

  char* ws = (char*)d_ws;
  size_t off = 0;
  auto alloc = [&](size_t b) { char* p = ws + off; off += (b + 255) & ~(size_t)255; return p; };
  unsigned short* xbuf = (unsigned short*)alloc((size_t)N_NODES * DIM * 2);
  unsigned short* hbuf = (unsigned short*)alloc((size_t)N_NODES * DIM * 2);
  unsigned short* WT   = (unsigned short*)alloc((size_t)NLAYERS * DIM * DIM * 2);
  float* als   = (float*)alloc((size_t)N_NODES * NH * 4);
  float* ald   = (float*)alloc((size_t)N_NODES * NH * 4);
  int* eidx    = (int*)alloc((size_t)2 * NE * 4);
  int* counts  = (int*)alloc((size_t)N_NODES * 4);
  int* offs    = (int*)alloc(((size_t)N_NODES + 1) * 4);
  int* cursor  = (int*)alloc((size_t)N_NODES * 4);
  int* csrc    = (int*)alloc((size_t)ETOT * 4);
  float* sums  = (float*)alloc(1024 * 4);
  float* scale = (float*)alloc(512 * 4);
  float* shift = (float*)alloc(512 * 4);

  convert_x_r4<<<(N_NODES * DIM / 8) / 256, 256, 0, stream>>>(x_in, xbuf);
  transpose_w_r4<<<dim3(16, 16, 5), 256, 0, stream>>>(Ws, WT);
  repack_edges_r4<<<(2 * NE) / 256, 256, 0, stream>>>(ei, eidx);
  init_counts_r4<<<N_NODES / 256, 256, 0, stream>>>(counts);
  hist_dst_r4<<<NE / 256, 256, 0, stream>>>(eidx, counts);
  scan_kernel_r4<<<1, 1024, 0, stream>>>(counts, offs, cursor);
  scatter_edges_r4<<<ETOT / 256, 256, 0, stream>>>(eidx, cursor, csrc);

  for (int l = 0; l < NLAYERS; l++) {
    // layer 0 consumes converted x directly; layers 1+ consume raw agg output
    // with BN+ReLU fused into A staging (scale/shift from previous layer).
    gemm_bt_r4<<<dim3(N_NODES / 128, DIM / 128), 256, 0, stream>>>(
        xbuf, WT + (size_t)l * DIM * DIM, scale, shift, (l > 0) ? 1 : 0, hbuf);
    attn_logits_r4<<<N_NODES / 4, 256, 0, stream>>>(hbuf, Asrc + l * NH * DHEAD, Adst + l * NH * DHEAD, als, ald);
    gat_agg_r4<<<N_NODES / 4, 256, 0, stream>>>(hbuf, als, ald, offs, csrc, Bconv + l * DIM, xbuf);
    zero_sums_r4<<<1, 256, 0, stream>>>(sums);
    bn_stats_r4<<<N_NODES / 32, 256, 0, stream>>>(xbuf, sums);
    bn_finalize_r4<<<1, 512, 0, stream>>>(sums, Gamma + l * DIM, Beta + l * DIM, scale, shift);
  }
  final_head_r4<<<N_NODES / 4, 256, 0, stream>>>(xbuf, scale, shift, Wl, bl, out);
}

// Round 5
// 1085.075 us; speedup vs baseline: 2.4019x; 2.4019x over previous
//
#include <hip/hip_runtime.h>
#include <cstdint>

#define N_NODES 49152
#define DIM 512
#define NH 8
#define DHEAD 64
#define NE 131072
#define ETOT (NE + N_NODES)   /* 180224 */
#define NLAYERS 5

typedef short short8 __attribute__((ext_vector_type(8)));
typedef float floatx4 __attribute__((ext_vector_type(4)));

__device__ __forceinline__ float bf2f(unsigned short v) {
  union { unsigned int u; float f; } x; x.u = ((unsigned int)v) << 16; return x.f;
}
__device__ __forceinline__ unsigned short f2bf(float f) {
  union { float f; unsigned int u; } x; x.f = f;
  unsigned int r = x.u + 0x7fffu + ((x.u >> 16) & 1u);
  return (unsigned short)(r >> 16);
}
__device__ __forceinline__ void async_load16(const void* g, void* l) {
  __builtin_amdgcn_global_load_lds((const __attribute__((address_space(1))) void*)g,
                                   (__attribute__((address_space(3))) void*)l, 16, 0, 0);
}

// ---------------- x: fp32 -> bf16 ----------------
__global__ __launch_bounds__(256) void convert_x_r5(const float* __restrict__ xf, unsigned short* __restrict__ xb)
{
  const size_t i = ((size_t)blockIdx.x * 256 + threadIdx.x) * 8;
  const float4 a = *(const float4*)&xf[i];
  const float4 b = *(const float4*)&xf[i + 4];
  unsigned int ov[4];
  ov[0] = (unsigned int)f2bf(a.x) | ((unsigned int)f2bf(a.y) << 16);
  ov[1] = (unsigned int)f2bf(a.z) | ((unsigned int)f2bf(a.w) << 16);
  ov[2] = (unsigned int)f2bf(b.x) | ((unsigned int)f2bf(b.y) << 16);
  ov[3] = (unsigned int)f2bf(b.z) | ((unsigned int)f2bf(b.w) << 16);
  *(uint4*)&xb[i] = *(const uint4*)ov;
}

// ---------------- W transpose + convert: WT[l][n][k] = bf16(Ws[l][k][n]) ----------------
__global__ void transpose_w_r5(const float* __restrict__ Ws, unsigned short* __restrict__ WT)
{
  __shared__ float tile[32][33];
  const int l  = blockIdx.z;
  const int nt = blockIdx.x * 32, kt = blockIdx.y * 32;
  const int tx = threadIdx.x & 31, ty = threadIdx.x >> 5;   // 256 threads
  #pragma unroll
  for (int r = 0; r < 32; r += 8)
    tile[ty + r][tx] = Ws[(size_t)l*DIM*DIM + (size_t)(kt + ty + r)*DIM + nt + tx];
  __syncthreads();
  #pragma unroll
  for (int r = 0; r < 32; r += 8)
    WT[(size_t)l*DIM*DIM + (size_t)(nt + ty + r)*DIM + kt + tx] = f2bf(tile[tx][ty + r]);
}

// ---------------- edge index canonicalize (auto-detect int64 vs int32) ----------------
__global__ void repack_edges_r5(const int* __restrict__ raw, int* __restrict__ eidx)
{
  const int i = blockIdx.x * 256 + threadIdx.x;    // 2*NE threads
  bool is64 = true;
  #pragma unroll
  for (int j = 0; j < 16; j++) is64 = is64 && (raw[2*j + 1] == 0);
  int v;
  if (is64) v = (int)((const long long*)raw)[i];
  else      v = raw[i];
  eidx[i] = v;
}

// ---------------- CSR build ----------------
__global__ void init_counts_r5(int* __restrict__ counts) {
  counts[blockIdx.x * 256 + threadIdx.x] = 1;    // self-loop
}
__global__ void hist_dst_r5(const int* __restrict__ eidx, int* __restrict__ counts) {
  const int i = blockIdx.x * 256 + threadIdx.x;  // NE threads
  atomicAdd(&counts[eidx[NE + i]], 1);
}
__global__ void scan_kernel_r5(const int* __restrict__ counts, int* __restrict__ offs, int* __restrict__ cursor)
{
  __shared__ int tot[1024];
  const int t = threadIdx.x;
  const int base = t * 48;                       // N_NODES = 1024*48
  int s = 0;
  for (int i = 0; i < 48; i++) s += counts[base + i];
  tot[t] = s;
  __syncthreads();
  for (int o = 1; o < 1024; o <<= 1) {
    int v = (t >= o) ? tot[t - o] : 0;
    __syncthreads();
    tot[t] += v;
    __syncthreads();
  }
  int run = tot[t] - s;
  for (int i = 0; i < 48; i++) {
    offs[base + i] = run;
    cursor[base + i] = run;
    run += counts[base + i];
  }
  if (t == 1023) offs[N_NODES] = tot[1023];
}
__global__ void scatter_edges_r5(const int* __restrict__ eidx, int* __restrict__ cursor, int* __restrict__ csrc)
{
  const int i = blockIdx.x * 256 + threadIdx.x;  // ETOT threads
  int s, d;
  if (i < NE) { s = eidx[i]; d = eidx[NE + i]; }
  else        { s = i - NE; d = s; }
  const int pos = atomicAdd(&cursor[d], 1);
  csrc[pos] = s;
}

// ---------------- GEMM: C[M,512] = A[M,512] @ BT[512,512]^T (bf16 MFMA, async staging) ----------------
__global__ __launch_bounds__(256) void gemm_bt_r5(const unsigned short* __restrict__ A,
                                                  const unsigned short* __restrict__ BT,
                                                  unsigned short* __restrict__ C)
{
  __shared__ unsigned short As[128 * 64];
  __shared__ unsigned short Bs[128 * 64];
  const int m0 = blockIdx.x * 128;
  const int n0 = blockIdx.y * 128;
  const int tid = threadIdx.x;
  const int wv = tid >> 6, lane = tid & 63;
  const int wr = (wv >> 1) * 64, wc = (wv & 1) * 64;
  const int q = lane >> 4, c16 = lane & 15;
  const int arow = lane >> 3;          // 0..7 within an 8-row chunk
  const int acol = (lane & 7) * 8;     // k offset within BK

  floatx4 acc[4][4] = {};

  for (int k0 = 0; k0 < DIM; k0 += 64) {
    #pragma unroll
    for (int t = 0; t < 4; t++) {
      const int cb = wv * 4 + t;       // chunk 0..15: 8 rows x 64 k (1 KiB)
      async_load16(A  + (size_t)(m0 + cb*8 + arow)*DIM + k0 + acol, &As[cb * 512]);
      async_load16(BT + (size_t)(n0 + cb*8 + arow)*DIM + k0 + acol, &Bs[cb * 512]);
    }
    __syncthreads();
    #pragma unroll
    for (int kk = 0; kk < 64; kk += 32) {
      short8 aF[4], bF[4];
      #pragma unroll
      for (int mt = 0; mt < 4; mt++)
        aF[mt] = *(const short8*)&As[(wr + mt*16 + c16) * 64 + kk + q*8];
      #pragma unroll
      for (int nt = 0; nt < 4; nt++)
        bF[nt] = *(const short8*)&Bs[(wc + nt*16 + c16) * 64 + kk + q*8];
      #pragma unroll
      for (int mt = 0; mt < 4; mt++)
        #pragma unroll
        for (int nt = 0; nt < 4; nt++)
          acc[mt][nt] = __builtin_amdgcn_mfma_f32_16x16x32_bf16(aF[mt], bF[nt], acc[mt][nt], 0, 0, 0);
    }
    __syncthreads();
  }
  // C/D layout (verified m89/m91): col = lane&15, row = (lane>>4)*4 + reg
  #pragma unroll
  for (int mt = 0; mt < 4; mt++) {
    #pragma unroll
    for (int nt = 0; nt < 4; nt++) {
      const int col = n0 + wc + nt*16 + c16;
      #pragma unroll
      for (int r = 0; r < 4; r++) {
        const int row = m0 + wr + mt*16 + q*4 + r;
        C[(size_t)row * DIM + col] = f2bf(acc[mt][nt][r]);
      }
    }
  }
}

// ---------------- attention logits ----------------
__global__ __launch_bounds__(256) void attn_logits_r5(const unsigned short* __restrict__ Hm,
    const float* __restrict__ asrc, const float* __restrict__ adst,
    float* __restrict__ als, float* __restrict__ ald)
{
  const int wv = threadIdx.x >> 6, lane = threadIdx.x & 63;
  const int node = blockIdx.x * 4 + wv;
  const int hd = lane >> 3;
  const uint4 hv = *(const uint4*)&Hm[(size_t)node * DIM + lane * 8];
  const unsigned int* hp = (const unsigned int*)&hv;
  const float4 sA = ((const float4*)(asrc + (size_t)lane * 8))[0];
  const float4 sB = ((const float4*)(asrc + (size_t)lane * 8))[1];
  const float4 dA = ((const float4*)(adst + (size_t)lane * 8))[0];
  const float4 dB = ((const float4*)(adst + (size_t)lane * 8))[1];
  const float sarr[8] = {sA.x, sA.y, sA.z, sA.w, sB.x, sB.y, sB.z, sB.w};
  const float darr[8] = {dA.x, dA.y, dA.z, dA.w, dB.x, dB.y, dB.z, dB.w};
  float ss = 0.f, sd = 0.f;
  #pragma unroll
  for (int i = 0; i < 4; i++) {
    const float h0 = bf2f((unsigned short)(hp[i] & 0xffffu));
    const float h1 = bf2f((unsigned short)(hp[i] >> 16));
    ss += h0 * sarr[2*i] + h1 * sarr[2*i + 1];
    sd += h0 * darr[2*i] + h1 * darr[2*i + 1];
  }
  #pragma unroll
  for (int msk = 1; msk <= 4; msk <<= 1) {
    ss += __shfl_xor(ss, msk, 64);
    sd += __shfl_xor(sd, msk, 64);
  }
  if ((lane & 7) == 0) {
    als[node * NH + hd] = ss;
    ald[node * NH + hd] = sd;
  }
}

// ---------------- GAT aggregate (softmax over CSR segment) + bias ----------------
__global__ __launch_bounds__(256) void gat_agg_r5(const unsigned short* __restrict__ Hm,
    const float* __restrict__ als, const float* __restrict__ ald,
    const int* __restrict__ offs, const int* __restrict__ csrc,
    const float* __restrict__ bconv, unsigned short* __restrict__ Xout)
{
  const int wv = threadIdx.x >> 6, lane = threadIdx.x & 63;
  const int node = blockIdx.x * 4 + wv;
  const int hd = lane >> 3;
  const float aldv = ald[node * NH + hd];
  const int e0 = offs[node], e1 = offs[node + 1];
  float m = -1e30f, z = 0.f;
  for (int e = e0; e < e1; e++) {
    const int s = csrc[e];
    float lg = als[s * NH + hd] + aldv;
    lg = lg > 0.f ? lg : 0.2f * lg;
    const float mn = fmaxf(m, lg);
    z = z * __expf(m - mn) + __expf(lg - mn);
    m = mn;
  }
  const float zinv = 1.f / (z + 1e-16f);
  float acc[8] = {};
  for (int e = e0; e < e1; e++) {
    const int s = csrc[e];
    float lg = als[s * NH + hd] + aldv;
    lg = lg > 0.f ? lg : 0.2f * lg;
    const float w = __expf(lg - m) * zinv;
    const uint4 hv = *(const uint4*)&Hm[(size_t)s * DIM + lane * 8];
    const unsigned int* hp = (const unsigned int*)&hv;
    #pragma unroll
    for (int j = 0; j < 4; j++) {
      acc[2*j]   += w * bf2f((unsigned short)(hp[j] & 0xffffu));
      acc[2*j+1] += w * bf2f((unsigned short)(hp[j] >> 16));
    }
  }
  const float4 bA = ((const float4*)(bconv + (size_t)lane * 8))[0];
  const float4 bB = ((const float4*)(bconv + (size_t)lane * 8))[1];
  const float barr[8] = {bA.x, bA.y, bA.z, bA.w, bB.x, bB.y, bB.z, bB.w};
  unsigned int ov[4];
  #pragma unroll
  for (int j = 0; j < 4; j++) {
    ov[j] = (unsigned int)f2bf(acc[2*j] + barr[2*j])
          | ((unsigned int)f2bf(acc[2*j+1] + barr[2*j+1]) << 16);
  }
  *(uint4*)&Xout[(size_t)node * DIM + lane * 8] = *(const uint4*)ov;
}

// ---------------- BatchNorm stats: two-stage, no global atomics ----------------
// Stage 1: 512 blocks x 96 rows. Per-block column partials via conflict-free LDS.
__global__ __launch_bounds__(256) void bn_stats1_r5(const unsigned short* __restrict__ X,
                                                    float* __restrict__ ps, float* __restrict__ pq)
{
  __shared__ float red[4][1024];     // [wave][j*64+cg] -> lane-consecutive, conflict-free
  const int t = threadIdx.x;
  const int g = t >> 6, cg = t & 63;
  const int c0 = cg * 8;
  const int r0 = blockIdx.x * 96;
  float s[8] = {}, qq[8] = {};
  for (int it = 0; it < 24; it++) {
    const int row = r0 + it * 4 + g;
    const uint4 v = *(const uint4*)&X[(size_t)row * DIM + c0];
    const unsigned int* vp = (const unsigned int*)&v;
    #pragma unroll
    for (int j = 0; j < 4; j++) {
      const float a = bf2f((unsigned short)(vp[j] & 0xffffu));
      const float b = bf2f((unsigned short)(vp[j] >> 16));
      s[2*j] += a;   qq[2*j] += a * a;
      s[2*j+1] += b; qq[2*j+1] += b * b;
    }
  }
  #pragma unroll
  for (int j = 0; j < 8; j++) {
    red[g][j * 64 + cg] = s[j];
    red[g][(j + 8) * 64 + cg] = qq[j];
  }
  __syncthreads();
  #pragma unroll
  for (int r = 0; r < 2; r++) {
    const int c = t + r * 256;              // 0..511
    const int cgg = c >> 3, j = c & 7;
    const float sv = red[0][j*64+cgg] + red[1][j*64+cgg] + red[2][j*64+cgg] + red[3][j*64+cgg];
    const float qv = red[0][(j+8)*64+cgg] + red[1][(j+8)*64+cgg] + red[2][(j+8)*64+cgg] + red[3][(j+8)*64+cgg];
    ps[(size_t)blockIdx.x * 512 + c] = sv;
    pq[(size_t)blockIdx.x * 512 + c] = qv;
  }
}
// Stage 2: reduce 512 partials per column + finalize scale/shift. 2 blocks x 256.
__global__ __launch_bounds__(256) void bn_stats2_r5(const float* __restrict__ ps, const float* __restrict__ pq,
                                                    const float* __restrict__ gamma, const float* __restrict__ beta,
                                                    float* __restrict__ scale, float* __restrict__ shift)
{
  const int c = blockIdx.x * 256 + threadIdx.x;  // 0..511
  float s = 0.f, q = 0.f;
  #pragma unroll 4
  for (int b = 0; b < 512; b++) {
    s += ps[(size_t)b * 512 + c];
    q += pq[(size_t)b * 512 + c];
  }
  const float inv = 1.0f / (float)N_NODES;
  const float mean = s * inv;
  float var = q * inv - mean * mean;
  var = fmaxf(var, 0.f);
  const float rs = rsqrtf(var + 1e-5f);
  const float sc = gamma[c] * rs;
  scale[c] = sc;
  shift[c] = beta[c] - mean * sc;
}

// ---------------- BN apply (in-place, layers 0..3) ----------------
__global__ __launch_bounds__(256) void bn_apply_r5(unsigned short* __restrict__ X,
    const float* __restrict__ scale, const float* __restrict__ shift)
{
  const size_t i = ((size_t)blockIdx.x * 256 + threadIdx.x) * 8;
  const int c = (int)(i & (DIM - 1));
  uint4 v = *(const uint4*)&X[i];
  unsigned int* vp = (unsigned int*)&v;
  unsigned int ov[4];
  #pragma unroll
  for (int j = 0; j < 4; j++) {
    const float a = bf2f((unsigned short)(vp[j] & 0xffffu));
    const float b = bf2f((unsigned short)(vp[j] >> 16));
    const float ya = fmaxf(0.f, a * scale[c + 2*j]     + shift[c + 2*j]);
    const float yb = fmaxf(0.f, b * scale[c + 2*j + 1] + shift[c + 2*j + 1]);
    ov[j] = (unsigned int)f2bf(ya) | ((unsigned int)f2bf(yb) << 16);
  }
  *(uint4*)&X[i] = *(const uint4*)ov;
}

// ---------------- final head: out[n] = relu(bn(X[n,:])) . Wl + bl ----------------
__global__ __launch_bounds__(256) void final_head_r5(const unsigned short* __restrict__ X,
    const float* __restrict__ scale, const float* __restrict__ shift,
    const float* __restrict__ wl, const float* __restrict__ blp,
    float* __restrict__ out)
{
  const int wv = threadIdx.x >> 6, lane = threadIdx.x & 63;
  const int node = blockIdx.x * 4 + wv;
  const uint4 xv = *(const uint4*)&X[(size_t)node * DIM + lane * 8];
  const unsigned int* xp = (const unsigned int*)&xv;
  const int c0 = lane * 8;
  float s = 0.f;
  #pragma unroll
  for (int i = 0; i < 4; i++) {
    const float a0 = bf2f((unsigned short)(xp[i] & 0xffffu));
    const float a1 = bf2f((unsigned short)(xp[i] >> 16));
    const float y0 = fmaxf(0.f, a0 * scale[c0 + 2*i]     + shift[c0 + 2*i]);
    const float y1 = fmaxf(0.f, a1 * scale[c0 + 2*i + 1] + shift[c0 + 2*i + 1]);
    s += y0 * wl[c0 + 2*i] + y1 * wl[c0 + 2*i + 1];
  }
  #pragma unroll
  for (int msk = 32; msk >= 1; msk >>= 1) s += __shfl_xor(s, msk, 64);
  if (lane == 0) out[node] = s + blp[0];
}

extern "C" void kernel_launch(void* const* d_in, const int* in_sizes, int n_in,
                              void* d_out, int out_size, void* d_ws, size_t ws_size,
                              hipStream_t stream)
{
  const float* x_in  = (const float*)d_in[0];
  const int*   ei    = (const int*)d_in[1];
  const float* Ws    = (const float*)d_in[2];
  const float* Asrc  = (const float*)d_in[3];
  const float* Adst  = (const float*)d_in[4];
  const float* Bconv = (const float*)d_in[5];
  const float* Gamma = (const float*)d_in[6];
  const float* Beta  = (const float*)d_in[7];
  const float* Wl    = (const float*)d_in[8];
  const float* bl    = (const float*)d_in[9];
  float* out = (float*)d_out;

  char* ws = (char*)d_ws;
  size_t off = 0;
  auto alloc = [&](size_t b) { char* p = ws + off; off += (b + 255) & ~(size_t)255; return p; };
  unsigned short* xbuf = (unsigned short*)alloc((size_t)N_NODES * DIM * 2);
  unsigned short* hbuf = (unsigned short*)alloc((size_t)N_NODES * DIM * 2);
  unsigned short* WT   = (unsigned short*)alloc((size_t)NLAYERS * DIM * DIM * 2);
  float* als   = (float*)alloc((size_t)N_NODES * NH * 4);
  float* ald   = (float*)alloc((size_t)N_NODES * NH * 4);
  int* eidx    = (int*)alloc((size_t)2 * NE * 4);
  int* counts  = (int*)alloc((size_t)N_NODES * 4);
  int* offs    = (int*)alloc(((size_t)N_NODES + 1) * 4);
  int* cursor  = (int*)alloc((size_t)N_NODES * 4);
  int* csrc    = (int*)alloc((size_t)ETOT * 4);
  float* ps    = (float*)alloc((size_t)512 * 512 * 4);
  float* pq    = (float*)alloc((size_t)512 * 512 * 4);
  float* scale = (float*)alloc(512 * 4);
  float* shift = (float*)alloc(512 * 4);

  convert_x_r5<<<(N_NODES * DIM / 8) / 256, 256, 0, stream>>>(x_in, xbuf);
  transpose_w_r5<<<dim3(16, 16, 5), 256, 0, stream>>>(Ws, WT);
  repack_edges_r5<<<(2 * NE) / 256, 256, 0, stream>>>(ei, eidx);
  init_counts_r5<<<N_NODES / 256, 256, 0, stream>>>(counts);
  hist_dst_r5<<<NE / 256, 256, 0, stream>>>(eidx, counts);
  scan_kernel_r5<<<1, 1024, 0, stream>>>(counts, offs, cursor);
  scatter_edges_r5<<<ETOT / 256, 256, 0, stream>>>(eidx, cursor, csrc);

  for (int l = 0; l < NLAYERS; l++) {
    gemm_bt_r5<<<dim3(N_NODES / 128, DIM / 128), 256, 0, stream>>>(xbuf, WT + (size_t)l * DIM * DIM, hbuf);
    attn_logits_r5<<<N_NODES / 4, 256, 0, stream>>>(hbuf, Asrc + l * NH * DHEAD, Adst + l * NH * DHEAD, als, ald);
    gat_agg_r5<<<N_NODES / 4, 256, 0, stream>>>(hbuf, als, ald, offs, csrc, Bconv + l * DIM, xbuf);
    bn_stats1_r5<<<512, 256, 0, stream>>>(xbuf, ps, pq);
    bn_stats2_r5<<<2, 256, 0, stream>>>(ps, pq, Gamma + l * DIM, Beta + l * DIM, scale, shift);
    if (l < NLAYERS - 1)
      bn_apply_r5<<<(N_NODES * DIM / 8) / 256, 256, 0, stream>>>(xbuf, scale, shift);
  }
  final_head_r5<<<N_NODES / 4, 256, 0, stream>>>(xbuf, scale, shift, Wl, bl, out);
}

// Round 6
// 1020.774 us; speedup vs baseline: 2.5532x; 1.0630x over previous
//
#include <hip/hip_runtime.h>
#include <cstdint>

#define N_NODES 49152
#define DIM 512
#define NH 8
#define DHEAD 64
#define NE 131072
#define ETOT (NE + N_NODES)   /* 180224 */
#define NLAYERS 5

typedef short short8 __attribute__((ext_vector_type(8)));
typedef float floatx4 __attribute__((ext_vector_type(4)));

__device__ __forceinline__ float bf2f(unsigned short v) {
  union { unsigned int u; float f; } x; x.u = ((unsigned int)v) << 16; return x.f;
}
__device__ __forceinline__ unsigned short f2bf(float f) {
  union { float f; unsigned int u; } x; x.f = f;
  unsigned int r = x.u + 0x7fffu + ((x.u >> 16) & 1u);
  return (unsigned short)(r >> 16);
}
__device__ __forceinline__ void async_load16(const void* g, void* l) {
  __builtin_amdgcn_global_load_lds((const __attribute__((address_space(1))) void*)g,
                                   (__attribute__((address_space(3))) void*)l, 16, 0, 0);
}

// ---------------- x: fp32 -> bf16 ----------------
__global__ __launch_bounds__(256) void convert_x_r6(const float* __restrict__ xf, unsigned short* __restrict__ xb)
{
  const size_t i = ((size_t)blockIdx.x * 256 + threadIdx.x) * 8;
  const float4 a = *(const float4*)&xf[i];
  const float4 b = *(const float4*)&xf[i + 4];
  unsigned int ov[4];
  ov[0] = (unsigned int)f2bf(a.x) | ((unsigned int)f2bf(a.y) << 16);
  ov[1] = (unsigned int)f2bf(a.z) | ((unsigned int)f2bf(a.w) << 16);
  ov[2] = (unsigned int)f2bf(b.x) | ((unsigned int)f2bf(b.y) << 16);
  ov[3] = (unsigned int)f2bf(b.z) | ((unsigned int)f2bf(b.w) << 16);
  *(uint4*)&xb[i] = *(const uint4*)ov;
}

// ---------------- W transpose + convert: WT[l][n][k] = bf16(Ws[l][k][n]) ----------------
__global__ void transpose_w_r6(const float* __restrict__ Ws, unsigned short* __restrict__ WT)
{
  __shared__ float tile[32][33];
  const int l  = blockIdx.z;
  const int nt = blockIdx.x * 32, kt = blockIdx.y * 32;
  const int tx = threadIdx.x & 31, ty = threadIdx.x >> 5;   // 256 threads
  #pragma unroll
  for (int r = 0; r < 32; r += 8)
    tile[ty + r][tx] = Ws[(size_t)l*DIM*DIM + (size_t)(kt + ty + r)*DIM + nt + tx];
  __syncthreads();
  #pragma unroll
  for (int r = 0; r < 32; r += 8)
    WT[(size_t)l*DIM*DIM + (size_t)(nt + ty + r)*DIM + kt + tx] = f2bf(tile[tx][ty + r]);
}

// ---------------- edge index canonicalize (auto-detect int64 vs int32) ----------------
__global__ void repack_edges_r6(const int* __restrict__ raw, int* __restrict__ eidx)
{
  const int i = blockIdx.x * 256 + threadIdx.x;    // 2*NE threads
  bool is64 = true;
  #pragma unroll
  for (int j = 0; j < 16; j++) is64 = is64 && (raw[2*j + 1] == 0);
  int v;
  if (is64) v = (int)((const long long*)raw)[i];
  else      v = raw[i];
  eidx[i] = v;
}

// ---------------- CSR build ----------------
__global__ void init_counts_r6(int* __restrict__ counts) {
  counts[blockIdx.x * 256 + threadIdx.x] = 1;    // self-loop
}
__global__ void hist_dst_r6(const int* __restrict__ eidx, int* __restrict__ counts) {
  const int i = blockIdx.x * 256 + threadIdx.x;  // NE threads
  atomicAdd(&counts[eidx[NE + i]], 1);
}
__global__ void scan_kernel_r6(const int* __restrict__ counts, int* __restrict__ offs, int* __restrict__ cursor)
{
  __shared__ int tot[1024];
  const int t = threadIdx.x;
  const int base = t * 48;                       // N_NODES = 1024*48
  int s = 0;
  for (int i = 0; i < 48; i++) s += counts[base + i];
  tot[t] = s;
  __syncthreads();
  for (int o = 1; o < 1024; o <<= 1) {
    int v = (t >= o) ? tot[t - o] : 0;
    __syncthreads();
    tot[t] += v;
    __syncthreads();
  }
  int run = tot[t] - s;
  for (int i = 0; i < 48; i++) {
    offs[base + i] = run;
    cursor[base + i] = run;
    run += counts[base + i];
  }
  if (t == 1023) offs[N_NODES] = tot[1023];
}
__global__ void scatter_edges_r6(const int* __restrict__ eidx, int* __restrict__ cursor, int* __restrict__ csrc)
{
  const int i = blockIdx.x * 256 + threadIdx.x;  // ETOT threads
  int s, d;
  if (i < NE) { s = eidx[i]; d = eidx[NE + i]; }
  else        { s = i - NE; d = s; }
  const int pos = atomicAdd(&cursor[d], 1);
  csrc[pos] = s;
}

// ---------------- GEMM + fused attention logits ----------------
// C[M,512] = A[M,512] @ BT^T. n-tile 128 = heads [2*by, 2*by+2); each wave's
// 64-col range = one full head, so logits reduce entirely from acc fragments.
__global__ __launch_bounds__(256) void gemm_bt_r6(const unsigned short* __restrict__ A,
                                                  const unsigned short* __restrict__ BT,
                                                  const float* __restrict__ asrc,
                                                  const float* __restrict__ adst,
                                                  unsigned short* __restrict__ C,
                                                  float* __restrict__ als,
                                                  float* __restrict__ ald)
{
  __shared__ unsigned short As[128 * 64];
  __shared__ unsigned short Bs[128 * 64];
  const int m0 = blockIdx.x * 128;
  const int n0 = blockIdx.y * 128;
  const int tid = threadIdx.x;
  const int wv = tid >> 6, lane = tid & 63;
  const int wr = (wv >> 1) * 64, wc = (wv & 1) * 64;
  const int q = lane >> 4, c16 = lane & 15;
  const int arow = lane >> 3;          // 0..7 within an 8-row chunk
  const int acol = (lane & 7) * 8;     // k offset within BK

  floatx4 acc[4][4] = {};

  for (int k0 = 0; k0 < DIM; k0 += 64) {
    #pragma unroll
    for (int t = 0; t < 4; t++) {
      const int cb = wv * 4 + t;       // chunk 0..15: 8 rows x 64 k (1 KiB)
      async_load16(A  + (size_t)(m0 + cb*8 + arow)*DIM + k0 + acol, &As[cb * 512]);
      async_load16(BT + (size_t)(n0 + cb*8 + arow)*DIM + k0 + acol, &Bs[cb * 512]);
    }
    __syncthreads();
    #pragma unroll
    for (int kk = 0; kk < 64; kk += 32) {
      short8 aF[4], bF[4];
      #pragma unroll
      for (int mt = 0; mt < 4; mt++)
        aF[mt] = *(const short8*)&As[(wr + mt*16 + c16) * 64 + kk + q*8];
      #pragma unroll
      for (int nt = 0; nt < 4; nt++)
        bF[nt] = *(const short8*)&Bs[(wc + nt*16 + c16) * 64 + kk + q*8];
      #pragma unroll
      for (int mt = 0; mt < 4; mt++)
        #pragma unroll
        for (int nt = 0; nt < 4; nt++)
          acc[mt][nt] = __builtin_amdgcn_mfma_f32_16x16x32_bf16(aF[mt], bF[nt], acc[mt][nt], 0, 0, 0);
    }
    __syncthreads();
  }
  // C/D layout (verified m89/m91): col = lane&15, row = (lane>>4)*4 + reg
  #pragma unroll
  for (int mt = 0; mt < 4; mt++) {
    #pragma unroll
    for (int nt = 0; nt < 4; nt++) {
      const int col = n0 + wc + nt*16 + c16;
      #pragma unroll
      for (int r = 0; r < 4; r++) {
        const int row = m0 + wr + mt*16 + q*4 + r;
        C[(size_t)row * DIM + col] = f2bf(acc[mt][nt][r]);
      }
    }
  }
  // fused logits: this wave's head covers cols [wc, wc+64) of this n-tile
  const int head = 2 * blockIdx.y + (wc >> 6);
  float as_[4], ad_[4];
  #pragma unroll
  for (int nt = 0; nt < 4; nt++) {
    const int d = nt * 16 + c16;                 // 0..63 within head
    as_[nt] = asrc[head * DHEAD + d];
    ad_[nt] = adst[head * DHEAD + d];
  }
  #pragma unroll
  for (int mt = 0; mt < 4; mt++) {
    #pragma unroll
    for (int r = 0; r < 4; r++) {
      float ss = 0.f, sd = 0.f;
      #pragma unroll
      for (int nt = 0; nt < 4; nt++) {
        ss += acc[mt][nt][r] * as_[nt];
        sd += acc[mt][nt][r] * ad_[nt];
      }
      #pragma unroll
      for (int msk = 1; msk <= 8; msk <<= 1) {   // reduce over the 16 c16 lanes
        ss += __shfl_xor(ss, msk, 64);
        sd += __shfl_xor(sd, msk, 64);
      }
      if (c16 == 0) {
        const int row = m0 + wr + mt*16 + q*4 + r;
        als[row * NH + head] = ss;
        ald[row * NH + head] = sd;
      }
    }
  }
}

// ---------------- GAT aggregate: single-pass online softmax + bias ----------------
__global__ __launch_bounds__(256) void gat_agg_r6(const unsigned short* __restrict__ Hm,
    const float* __restrict__ als, const float* __restrict__ ald,
    const int* __restrict__ offs, const int* __restrict__ csrc,
    const float* __restrict__ bconv, unsigned short* __restrict__ Xout)
{
  const int wv = threadIdx.x >> 6, lane = threadIdx.x & 63;
  const int node = blockIdx.x * 4 + wv;
  const int hd = lane >> 3;
  const float aldv = ald[node * NH + hd];
  const int e0 = offs[node], e1 = offs[node + 1];
  float m = -1e30f, z = 0.f;
  float acc[8] = {};
  for (int e = e0; e < e1; e++) {
    const int s = csrc[e];
    float lg = als[s * NH + hd] + aldv;
    lg = lg > 0.f ? lg : 0.2f * lg;
    const float mn = fmaxf(m, lg);
    const float sf = __expf(m - mn);       // 0 on first iter (m=-1e30)
    const float w  = __expf(lg - mn);
    z = z * sf + w;
    const uint4 hv = *(const uint4*)&Hm[(size_t)s * DIM + lane * 8];
    const unsigned int* hp = (const unsigned int*)&hv;
    #pragma unroll
    for (int j = 0; j < 4; j++) {
      acc[2*j]   = acc[2*j]   * sf + w * bf2f((unsigned short)(hp[j] & 0xffffu));
      acc[2*j+1] = acc[2*j+1] * sf + w * bf2f((unsigned short)(hp[j] >> 16));
    }
    m = mn;
  }
  const float zinv = 1.f / (z + 1e-16f);
  const float4 bA = ((const float4*)(bconv + (size_t)lane * 8))[0];
  const float4 bB = ((const float4*)(bconv + (size_t)lane * 8))[1];
  const float barr[8] = {bA.x, bA.y, bA.z, bA.w, bB.x, bB.y, bB.z, bB.w};
  unsigned int ov[4];
  #pragma unroll
  for (int j = 0; j < 4; j++) {
    ov[j] = (unsigned int)f2bf(acc[2*j] * zinv + barr[2*j])
          | ((unsigned int)f2bf(acc[2*j+1] * zinv + barr[2*j+1]) << 16);
  }
  *(uint4*)&Xout[(size_t)node * DIM + lane * 8] = *(const uint4*)ov;
}

// ---------------- BatchNorm stats: two-stage, no global atomics ----------------
__global__ __launch_bounds__(256) void bn_stats1_r6(const unsigned short* __restrict__ X,
                                                    float* __restrict__ ps, float* __restrict__ pq)
{
  __shared__ float red[4][1024];     // [wave][j*64+cg] -> lane-consecutive, conflict-free
  const int t = threadIdx.x;
  const int g = t >> 6, cg = t & 63;
  const int c0 = cg * 8;
  const int r0 = blockIdx.x * 96;
  float s[8] = {}, qq[8] = {};
  for (int it = 0; it < 24; it++) {
    const int row = r0 + it * 4 + g;
    const uint4 v = *(const uint4*)&X[(size_t)row * DIM + c0];
    const unsigned int* vp = (const unsigned int*)&v;
    #pragma unroll
    for (int j = 0; j < 4; j++) {
      const float a = bf2f((unsigned short)(vp[j] & 0xffffu));
      const float b = bf2f((unsigned short)(vp[j] >> 16));
      s[2*j] += a;   qq[2*j] += a * a;
      s[2*j+1] += b; qq[2*j+1] += b * b;
    }
  }
  #pragma unroll
  for (int j = 0; j < 8; j++) {
    red[g][j * 64 + cg] = s[j];
    red[g][(j + 8) * 64 + cg] = qq[j];
  }
  __syncthreads();
  #pragma unroll
  for (int r = 0; r < 2; r++) {
    const int c = t + r * 256;              // 0..511
    const int cgg = c >> 3, j = c & 7;
    const float sv = red[0][j*64+cgg] + red[1][j*64+cgg] + red[2][j*64+cgg] + red[3][j*64+cgg];
    const float qv = red[0][(j+8)*64+cgg] + red[1][(j+8)*64+cgg] + red[2][(j+8)*64+cgg] + red[3][(j+8)*64+cgg];
    ps[(size_t)blockIdx.x * 512 + c] = sv;
    pq[(size_t)blockIdx.x * 512 + c] = qv;
  }
}
__global__ __launch_bounds__(256) void bn_stats2_r6(const float* __restrict__ ps, const float* __restrict__ pq,
                                                    const float* __restrict__ gamma, const float* __restrict__ beta,
                                                    float* __restrict__ scale, float* __restrict__ shift)
{
  const int c = blockIdx.x * 256 + threadIdx.x;  // 0..511
  float s = 0.f, q = 0.f;
  #pragma unroll 4
  for (int b = 0; b < 512; b++) {
    s += ps[(size_t)b * 512 + c];
    q += pq[(size_t)b * 512 + c];
  }
  const float inv = 1.0f / (float)N_NODES;
  const float mean = s * inv;
  float var = q * inv - mean * mean;
  var = fmaxf(var, 0.f);
  const float rs = rsqrtf(var + 1e-5f);
  const float sc = gamma[c] * rs;
  scale[c] = sc;
  shift[c] = beta[c] - mean * sc;
}

// ---------------- BN apply (in-place, layers 0..3) ----------------
__global__ __launch_bounds__(256) void bn_apply_r6(unsigned short* __restrict__ X,
    const float* __restrict__ scale, const float* __restrict__ shift)
{
  const size_t i = ((size_t)blockIdx.x * 256 + threadIdx.x) * 8;
  const int c = (int)(i & (DIM - 1));
  uint4 v = *(const uint4*)&X[i];
  unsigned int* vp = (unsigned int*)&v;
  unsigned int ov[4];
  #pragma unroll
  for (int j = 0; j < 4; j++) {
    const float a = bf2f((unsigned short)(vp[j] & 0xffffu));
    const float b = bf2f((unsigned short)(vp[j] >> 16));
    const float ya = fmaxf(0.f, a * scale[c + 2*j]     + shift[c + 2*j]);
    const float yb = fmaxf(0.f, b * scale[c + 2*j + 1] + shift[c + 2*j + 1]);
    ov[j] = (unsigned int)f2bf(ya) | ((unsigned int)f2bf(yb) << 16);
  }
  *(uint4*)&X[i] = *(const uint4*)ov;
}

// ---------------- final head: out[n] = relu(bn(X[n,:])) . Wl + bl ----------------
__global__ __launch_bounds__(256) void final_head_r6(const unsigned short* __restrict__ X,
    const float* __restrict__ scale, const float* __restrict__ shift,
    const float* __restrict__ wl, const float* __restrict__ blp,
    float* __restrict__ out)
{
  const int wv = threadIdx.x >> 6, lane = threadIdx.x & 63;
  const int node = blockIdx.x * 4 + wv;
  const uint4 xv = *(const uint4*)&X[(size_t)node * DIM + lane * 8];
  const unsigned int* xp = (const unsigned int*)&xv;
  const int c0 = lane * 8;
  float s = 0.f;
  #pragma unroll
  for (int i = 0; i < 4; i++) {
    const float a0 = bf2f((unsigned short)(xp[i] & 0xffffu));
    const float a1 = bf2f((unsigned short)(xp[i] >> 16));
    const float y0 = fmaxf(0.f, a0 * scale[c0 + 2*i]     + shift[c0 + 2*i]);
    const float y1 = fmaxf(0.f, a1 * scale[c0 + 2*i + 1] + shift[c0 + 2*i + 1]);
    s += y0 * wl[c0 + 2*i] + y1 * wl[c0 + 2*i + 1];
  }
  #pragma unroll
  for (int msk = 32; msk >= 1; msk >>= 1) s += __shfl_xor(s, msk, 64);
  if (lane == 0) out[node] = s + blp[0];
}

extern "C" void kernel_launch(void* const* d_in, const int* in_sizes, int n_in,
                              void* d_out, int out_size, void* d_ws, size_t ws_size,
                              hipStream_t stream)
{
  const float* x_in  = (const float*)d_in[0];
  const int*   ei    = (const int*)d_in[1];
  const float* Ws    = (const float*)d_in[2];
  const float* Asrc  = (const float*)d_in[3];
  const float* Adst  = (const float*)d_in[4];
  const float* Bconv = (const float*)d_in[5];
  const float* Gamma = (const float*)d_in[6];
  const float* Beta  = (const float*)d_in[7];
  const float* Wl    = (const float*)d_in[8];
  const float* bl    = (const float*)d_in[9];
  float* out = (float*)d_out;

  char* ws = (char*)d_ws;
  size_t off = 0;
  auto alloc = [&](size_t b) { char* p = ws + off; off += (b + 255) & ~(size_t)255; return p; };
  unsigned short* xbuf = (unsigned short*)alloc((size_t)N_NODES * DIM * 2);
  unsigned short* hbuf = (unsigned short*)alloc((size_t)N_NODES * DIM * 2);
  unsigned short* WT   = (unsigned short*)alloc((size_t)NLAYERS * DIM * DIM * 2);
  float* als   = (float*)alloc((size_t)N_NODES * NH * 4);
  float* ald   = (float*)alloc((size_t)N_NODES * NH * 4);
  int* eidx    = (int*)alloc((size_t)2 * NE * 4);
  int* counts  = (int*)alloc((size_t)N_NODES * 4);
  int* offs    = (int*)alloc(((size_t)N_NODES + 1) * 4);
  int* cursor  = (int*)alloc((size_t)N_NODES * 4);
  int* csrc    = (int*)alloc((size_t)ETOT * 4);
  float* ps    = (float*)alloc((size_t)512 * 512 * 4);
  float* pq    = (float*)alloc((size_t)512 * 512 * 4);
  float* scale = (float*)alloc(512 * 4);
  float* shift = (float*)alloc(512 * 4);

  convert_x_r6<<<(N_NODES * DIM / 8) / 256, 256, 0, stream>>>(x_in, xbuf);
  transpose_w_r6<<<dim3(16, 16, 5), 256, 0, stream>>>(Ws, WT);
  repack_edges_r6<<<(2 * NE) / 256, 256, 0, stream>>>(ei, eidx);
  init_counts_r6<<<N_NODES / 256, 256, 0, stream>>>(counts);
  hist_dst_r6<<<NE / 256, 256, 0, stream>>>(eidx, counts);
  scan_kernel_r6<<<1, 1024, 0, stream>>>(counts, offs, cursor);
  scatter_edges_r6<<<ETOT / 256, 256, 0, stream>>>(eidx, cursor, csrc);

  for (int l = 0; l < NLAYERS; l++) {
    gemm_bt_r6<<<dim3(N_NODES / 128, DIM / 128), 256, 0, stream>>>(
        xbuf, WT + (size_t)l * DIM * DIM,
        Asrc + l * NH * DHEAD, Adst + l * NH * DHEAD, hbuf, als, ald);
    gat_agg_r6<<<N_NODES / 4, 256, 0, stream>>>(hbuf, als, ald, offs, csrc, Bconv + l * DIM, xbuf);
    bn_stats1_r6<<<512, 256, 0, stream>>>(xbuf, ps, pq);
    bn_stats2_r6<<<2, 256, 0, stream>>>(ps, pq, Gamma + l * DIM, Beta + l * DIM, scale, shift);
    if (l < NLAYERS - 1)
      bn_apply_r6<<<(N_NODES * DIM / 8) / 256, 256, 0, stream>>>(xbuf, scale, shift);
  }
  final_head_r6<<<N_NODES / 4, 256, 0, stream>>>(xbuf, scale, shift, Wl, bl, out);
}

// Round 7
// 814.959 us; speedup vs baseline: 3.1980x; 1.2525x over previous
//
#include <hip/hip_runtime.h>
#include <cstdint>

#define N_NODES 49152
#define DIM 512
#define NH 8
#define DHEAD 64
#define NE 131072
#define ETOT (NE + N_NODES)   /* 180224 */
#define NLAYERS 5
#define AGG_NODES 32          /* nodes per gat_agg block (4 waves x 8) */
#define AGG_BLOCKS (N_NODES / AGG_NODES)   /* 1536 */

typedef short short8 __attribute__((ext_vector_type(8)));
typedef float floatx4 __attribute__((ext_vector_type(4)));

__device__ __forceinline__ float bf2f(unsigned short v) {
  union { unsigned int u; float f; } x; x.u = ((unsigned int)v) << 16; return x.f;
}
__device__ __forceinline__ unsigned short f2bf(float f) {
  union { float f; unsigned int u; } x; x.f = f;
  unsigned int r = x.u + 0x7fffu + ((x.u >> 16) & 1u);
  return (unsigned short)(r >> 16);
}
__device__ __forceinline__ void async_load16(const void* g, void* l) {
  __builtin_amdgcn_global_load_lds((const __attribute__((address_space(1))) void*)g,
                                   (__attribute__((address_space(3))) void*)l, 16, 0, 0);
}

// ---------------- x: fp32 -> bf16 ----------------
__global__ __launch_bounds__(256) void convert_x_r7(const float* __restrict__ xf, unsigned short* __restrict__ xb)
{
  const size_t i = ((size_t)blockIdx.x * 256 + threadIdx.x) * 8;
  const float4 a = *(const float4*)&xf[i];
  const float4 b = *(const float4*)&xf[i + 4];
  unsigned int ov[4];
  ov[0] = (unsigned int)f2bf(a.x) | ((unsigned int)f2bf(a.y) << 16);
  ov[1] = (unsigned int)f2bf(a.z) | ((unsigned int)f2bf(a.w) << 16);
  ov[2] = (unsigned int)f2bf(b.x) | ((unsigned int)f2bf(b.y) << 16);
  ov[3] = (unsigned int)f2bf(b.z) | ((unsigned int)f2bf(b.w) << 16);
  *(uint4*)&xb[i] = *(const uint4*)ov;
}

// ---------------- W transpose + convert: WT[l][n][k] = bf16(Ws[l][k][n]) ----------------
__global__ void transpose_w_r7(const float* __restrict__ Ws, unsigned short* __restrict__ WT)
{
  __shared__ float tile[32][33];
  const int l  = blockIdx.z;
  const int nt = blockIdx.x * 32, kt = blockIdx.y * 32;
  const int tx = threadIdx.x & 31, ty = threadIdx.x >> 5;   // 256 threads
  #pragma unroll
  for (int r = 0; r < 32; r += 8)
    tile[ty + r][tx] = Ws[(size_t)l*DIM*DIM + (size_t)(kt + ty + r)*DIM + nt + tx];
  __syncthreads();
  #pragma unroll
  for (int r = 0; r < 32; r += 8)
    WT[(size_t)l*DIM*DIM + (size_t)(nt + ty + r)*DIM + kt + tx] = f2bf(tile[tx][ty + r]);
}

// ---------------- edge index canonicalize (auto-detect int64 vs int32) ----------------
__global__ void repack_edges_r7(const int* __restrict__ raw, int* __restrict__ eidx)
{
  const int i = blockIdx.x * 256 + threadIdx.x;    // 2*NE threads
  bool is64 = true;
  #pragma unroll
  for (int j = 0; j < 16; j++) is64 = is64 && (raw[2*j + 1] == 0);
  int v;
  if (is64) v = (int)((const long long*)raw)[i];
  else      v = raw[i];
  eidx[i] = v;
}

// ---------------- CSR build ----------------
__global__ void init_counts_r7(int* __restrict__ counts) {
  counts[blockIdx.x * 256 + threadIdx.x] = 1;    // self-loop
}
__global__ void hist_dst_r7(const int* __restrict__ eidx, int* __restrict__ counts) {
  const int i = blockIdx.x * 256 + threadIdx.x;  // NE threads
  atomicAdd(&counts[eidx[NE + i]], 1);
}
__global__ void scan_kernel_r7(const int* __restrict__ counts, int* __restrict__ offs, int* __restrict__ cursor)
{
  __shared__ int tot[1024];
  const int t = threadIdx.x;
  const int base = t * 48;                       // N_NODES = 1024*48
  int s = 0;
  for (int i = 0; i < 48; i++) s += counts[base + i];
  tot[t] = s;
  __syncthreads();
  for (int o = 1; o < 1024; o <<= 1) {
    int v = (t >= o) ? tot[t - o] : 0;
    __syncthreads();
    tot[t] += v;
    __syncthreads();
  }
  int run = tot[t] - s;
  for (int i = 0; i < 48; i++) {
    offs[base + i] = run;
    cursor[base + i] = run;
    run += counts[base + i];
  }
  if (t == 1023) offs[N_NODES] = tot[1023];
}
__global__ void scatter_edges_r7(const int* __restrict__ eidx, int* __restrict__ cursor, int* __restrict__ csrc)
{
  const int i = blockIdx.x * 256 + threadIdx.x;  // ETOT threads
  int s, d;
  if (i < NE) { s = eidx[i]; d = eidx[NE + i]; }
  else        { s = i - NE; d = s; }
  const int pos = atomicAdd(&cursor[d], 1);
  csrc[pos] = s;
}

// ---------------- GEMM 128m x 256n (8 waves) + fused attention logits ----------------
// C[M,512] = A[M,512] @ BT^T. n-tile 256 = heads [4*by, 4*by+4); each wave's
// 64-col slice is one full head; logits reduce from acc fragments.
__global__ __launch_bounds__(512, 4) void gemm_bt_r7(const unsigned short* __restrict__ A,
                                                     const unsigned short* __restrict__ BT,
                                                     const float* __restrict__ asrc,
                                                     const float* __restrict__ adst,
                                                     unsigned short* __restrict__ C,
                                                     float* __restrict__ als,
                                                     float* __restrict__ ald)
{
  __shared__ unsigned short As[128 * 64];   // 16 KiB
  __shared__ unsigned short Bs[256 * 64];   // 32 KiB
  const int m0 = blockIdx.x * 128;
  const int n0 = blockIdx.y * 256;
  const int tid = threadIdx.x;
  const int wv = tid >> 6, lane = tid & 63;         // 8 waves
  const int wr = (wv & 1) * 64, wc = (wv >> 1) * 64; // m 2 x n 4
  const int q = lane >> 4, c16 = lane & 15;
  const int arow = lane >> 3;          // 0..7 within an 8-row chunk
  const int acol = (lane & 7) * 8;     // k offset within BK

  floatx4 acc[4][4] = {};

  for (int k0 = 0; k0 < DIM; k0 += 64) {
    #pragma unroll
    for (int t = 0; t < 2; t++) {      // A: 16 chunks of 8 rows x 64 k
      const int cb = wv * 2 + t;
      async_load16(A + (size_t)(m0 + cb*8 + arow)*DIM + k0 + acol, &As[cb * 512]);
    }
    #pragma unroll
    for (int t = 0; t < 4; t++) {      // B: 32 chunks
      const int cb = wv * 4 + t;
      async_load16(BT + (size_t)(n0 + cb*8 + arow)*DIM + k0 + acol, &Bs[cb * 512]);
    }
    __syncthreads();
    #pragma unroll
    for (int kk = 0; kk < 64; kk += 32) {
      short8 aF[4], bF[4];
      #pragma unroll
      for (int mt = 0; mt < 4; mt++)
        aF[mt] = *(const short8*)&As[(wr + mt*16 + c16) * 64 + kk + q*8];
      #pragma unroll
      for (int nt = 0; nt < 4; nt++)
        bF[nt] = *(const short8*)&Bs[(wc + nt*16 + c16) * 64 + kk + q*8];
      #pragma unroll
      for (int mt = 0; mt < 4; mt++)
        #pragma unroll
        for (int nt = 0; nt < 4; nt++)
          acc[mt][nt] = __builtin_amdgcn_mfma_f32_16x16x32_bf16(aF[mt], bF[nt], acc[mt][nt], 0, 0, 0);
    }
    __syncthreads();
  }
  // C/D layout (verified m89/m91): col = lane&15, row = (lane>>4)*4 + reg
  #pragma unroll
  for (int mt = 0; mt < 4; mt++) {
    #pragma unroll
    for (int nt = 0; nt < 4; nt++) {
      const int col = n0 + wc + nt*16 + c16;
      #pragma unroll
      for (int r = 0; r < 4; r++) {
        const int row = m0 + wr + mt*16 + q*4 + r;
        C[(size_t)row * DIM + col] = f2bf(acc[mt][nt][r]);
      }
    }
  }
  // fused logits: this wave's head covers cols [wc, wc+64) of this n-tile
  const int head = 4 * blockIdx.y + (wc >> 6);
  float as_[4], ad_[4];
  #pragma unroll
  for (int nt = 0; nt < 4; nt++) {
    const int d = nt * 16 + c16;                 // 0..63 within head
    as_[nt] = asrc[head * DHEAD + d];
    ad_[nt] = adst[head * DHEAD + d];
  }
  #pragma unroll
  for (int mt = 0; mt < 4; mt++) {
    #pragma unroll
    for (int r = 0; r < 4; r++) {
      float ss = 0.f, sd = 0.f;
      #pragma unroll
      for (int nt = 0; nt < 4; nt++) {
        ss += acc[mt][nt][r] * as_[nt];
        sd += acc[mt][nt][r] * ad_[nt];
      }
      #pragma unroll
      for (int msk = 1; msk <= 8; msk <<= 1) {   // reduce over the 16 c16 lanes
        ss += __shfl_xor(ss, msk, 64);
        sd += __shfl_xor(sd, msk, 64);
      }
      if (c16 == 0) {
        const int row = m0 + wr + mt*16 + q*4 + r;
        als[row * NH + head] = ss;
        ald[row * NH + head] = sd;
      }
    }
  }
}

// ---------------- GAT aggregate (online softmax) + bias + fused BN partials ----------------
// 4 waves x 8 serial nodes per block; per-lane column partial sums of the
// (bf16-rounded) output accumulate across nodes -> per-block ps/pq.
__global__ __launch_bounds__(256) void gat_agg_r7(const unsigned short* __restrict__ Hm,
    const float* __restrict__ als, const float* __restrict__ ald,
    const int* __restrict__ offs, const int* __restrict__ csrc,
    const float* __restrict__ bconv, unsigned short* __restrict__ Xout,
    float* __restrict__ ps, float* __restrict__ pq)
{
  __shared__ float red[4][1024];
  const int wv = threadIdx.x >> 6, lane = threadIdx.x & 63;
  const int hd = lane >> 3;
  const float4 bA = ((const float4*)(bconv + (size_t)lane * 8))[0];
  const float4 bB = ((const float4*)(bconv + (size_t)lane * 8))[1];
  const float barr[8] = {bA.x, bA.y, bA.z, bA.w, bB.x, bB.y, bB.z, bB.w};
  float cs[8] = {}, cq[8] = {};

  for (int i = 0; i < 8; i++) {
    const int node = blockIdx.x * AGG_NODES + wv * 8 + i;
    const float aldv = ald[node * NH + hd];
    const int e0 = offs[node], e1 = offs[node + 1];
    float m = -1e30f, z = 0.f;
    float acc[8] = {};
    for (int e = e0; e < e1; e++) {
      const int s = csrc[e];
      float lg = als[s * NH + hd] + aldv;
      lg = lg > 0.f ? lg : 0.2f * lg;
      const float mn = fmaxf(m, lg);
      const float sf = __expf(m - mn);
      const float w  = __expf(lg - mn);
      z = z * sf + w;
      const uint4 hv = *(const uint4*)&Hm[(size_t)s * DIM + lane * 8];
      const unsigned int* hp = (const unsigned int*)&hv;
      #pragma unroll
      for (int j = 0; j < 4; j++) {
        acc[2*j]   = acc[2*j]   * sf + w * bf2f((unsigned short)(hp[j] & 0xffffu));
        acc[2*j+1] = acc[2*j+1] * sf + w * bf2f((unsigned short)(hp[j] >> 16));
      }
      m = mn;
    }
    const float zinv = 1.f / (z + 1e-16f);
    unsigned int ov[4];
    #pragma unroll
    for (int j = 0; j < 4; j++) {
      const unsigned short b0 = f2bf(acc[2*j] * zinv + barr[2*j]);
      const unsigned short b1 = f2bf(acc[2*j+1] * zinv + barr[2*j+1]);
      ov[j] = (unsigned int)b0 | ((unsigned int)b1 << 16);
      const float y0 = bf2f(b0), y1 = bf2f(b1);   // rounded values, matching bn_stats-on-xbuf
      cs[2*j]   += y0; cq[2*j]   += y0 * y0;
      cs[2*j+1] += y1; cq[2*j+1] += y1 * y1;
    }
    *(uint4*)&Xout[(size_t)node * DIM + lane * 8] = *(const uint4*)ov;
  }
  #pragma unroll
  for (int j = 0; j < 8; j++) {
    red[wv][lane * 8 + j] = cs[j];
    red[wv][512 + lane * 8 + j] = cq[j];
  }
  __syncthreads();
  const int t = threadIdx.x;
  #pragma unroll
  for (int r = 0; r < 2; r++) {
    const int c = t + r * 256;        // 0..511
    ps[(size_t)blockIdx.x * 512 + c] = red[0][c] + red[1][c] + red[2][c] + red[3][c];
    pq[(size_t)blockIdx.x * 512 + c] = red[0][512+c] + red[1][512+c] + red[2][512+c] + red[3][512+c];
  }
}

// ---------------- BN reduce+finalize: one block per column ----------------
__global__ __launch_bounds__(256) void bn_reduce_r7(const float* __restrict__ ps, const float* __restrict__ pq,
                                                    const float* __restrict__ gamma, const float* __restrict__ beta,
                                                    float* __restrict__ scale, float* __restrict__ shift)
{
  __shared__ float rs[256], rq[256];
  const int c = blockIdx.x;           // 0..511
  const int t = threadIdx.x;
  float s = 0.f, q = 0.f;
  for (int b = t; b < AGG_BLOCKS; b += 256) {
    s += ps[(size_t)b * 512 + c];
    q += pq[(size_t)b * 512 + c];
  }
  rs[t] = s; rq[t] = q;
  __syncthreads();
  for (int o = 128; o > 0; o >>= 1) {
    if (t < o) { rs[t] += rs[t + o]; rq[t] += rq[t + o]; }
    __syncthreads();
  }
  if (t == 0) {
    const float inv = 1.0f / (float)N_NODES;
    const float mean = rs[0] * inv;
    float var = rq[0] * inv - mean * mean;
    var = fmaxf(var, 0.f);
    const float rsq = rsqrtf(var + 1e-5f);
    const float sc = gamma[c] * rsq;
    scale[c] = sc;
    shift[c] = beta[c] - mean * sc;
  }
}

// ---------------- BN apply (in-place, layers 0..3) ----------------
__global__ __launch_bounds__(256) void bn_apply_r7(unsigned short* __restrict__ X,
    const float* __restrict__ scale, const float* __restrict__ shift)
{
  const size_t i = ((size_t)blockIdx.x * 256 + threadIdx.x) * 8;
  const int c = (int)(i & (DIM - 1));
  uint4 v = *(const uint4*)&X[i];
  unsigned int* vp = (unsigned int*)&v;
  unsigned int ov[4];
  #pragma unroll
  for (int j = 0; j < 4; j++) {
    const float a = bf2f((unsigned short)(vp[j] & 0xffffu));
    const float b = bf2f((unsigned short)(vp[j] >> 16));
    const float ya = fmaxf(0.f, a * scale[c + 2*j]     + shift[c + 2*j]);
    const float yb = fmaxf(0.f, b * scale[c + 2*j + 1] + shift[c + 2*j + 1]);
    ov[j] = (unsigned int)f2bf(ya) | ((unsigned int)f2bf(yb) << 16);
  }
  *(uint4*)&X[i] = *(const uint4*)ov;
}

// ---------------- final head: out[n] = relu(bn(X[n,:])) . Wl + bl ----------------
__global__ __launch_bounds__(256) void final_head_r7(const unsigned short* __restrict__ X,
    const float* __restrict__ scale, const float* __restrict__ shift,
    const float* __restrict__ wl, const float* __restrict__ blp,
    float* __restrict__ out)
{
  const int wv = threadIdx.x >> 6, lane = threadIdx.x & 63;
  const int node = blockIdx.x * 4 + wv;
  const uint4 xv = *(const uint4*)&X[(size_t)node * DIM + lane * 8];
  const unsigned int* xp = (const unsigned int*)&xv;
  const int c0 = lane * 8;
  float s = 0.f;
  #pragma unroll
  for (int i = 0; i < 4; i++) {
    const float a0 = bf2f((unsigned short)(xp[i] & 0xffffu));
    const float a1 = bf2f((unsigned short)(xp[i] >> 16));
    const float y0 = fmaxf(0.f, a0 * scale[c0 + 2*i]     + shift[c0 + 2*i]);
    const float y1 = fmaxf(0.f, a1 * scale[c0 + 2*i + 1] + shift[c0 + 2*i + 1]);
    s += y0 * wl[c0 + 2*i] + y1 * wl[c0 + 2*i + 1];
  }
  #pragma unroll
  for (int msk = 32; msk >= 1; msk >>= 1) s += __shfl_xor(s, msk, 64);
  if (lane == 0) out[node] = s + blp[0];
}

extern "C" void kernel_launch(void* const* d_in, const int* in_sizes, int n_in,
                              void* d_out, int out_size, void* d_ws, size_t ws_size,
                              hipStream_t stream)
{
  const float* x_in  = (const float*)d_in[0];
  const int*   ei    = (const int*)d_in[1];
  const float* Ws    = (const float*)d_in[2];
  const float* Asrc  = (const float*)d_in[3];
  const float* Adst  = (const float*)d_in[4];
  const float* Bconv = (const float*)d_in[5];
  const float* Gamma = (const float*)d_in[6];
  const float* Beta  = (const float*)d_in[7];
  const float* Wl    = (const float*)d_in[8];
  const float* bl    = (const float*)d_in[9];
  float* out = (float*)d_out;

  char* ws = (char*)d_ws;
  size_t off = 0;
  auto alloc = [&](size_t b) { char* p = ws + off; off += (b + 255) & ~(size_t)255; return p; };
  unsigned short* xbuf = (unsigned short*)alloc((size_t)N_NODES * DIM * 2);
  unsigned short* hbuf = (unsigned short*)alloc((size_t)N_NODES * DIM * 2);
  unsigned short* WT   = (unsigned short*)alloc((size_t)NLAYERS * DIM * DIM * 2);
  float* als   = (float*)alloc((size_t)N_NODES * NH * 4);
  float* ald   = (float*)alloc((size_t)N_NODES * NH * 4);
  int* eidx    = (int*)alloc((size_t)2 * NE * 4);
  int* counts  = (int*)alloc((size_t)N_NODES * 4);
  int* offs    = (int*)alloc(((size_t)N_NODES + 1) * 4);
  int* cursor  = (int*)alloc((size_t)N_NODES * 4);
  int* csrc    = (int*)alloc((size_t)ETOT * 4);
  float* ps    = (float*)alloc((size_t)AGG_BLOCKS * 512 * 4);
  float* pq    = (float*)alloc((size_t)AGG_BLOCKS * 512 * 4);
  float* scale = (float*)alloc(512 * 4);
  float* shift = (float*)alloc(512 * 4);

  convert_x_r7<<<(N_NODES * DIM / 8) / 256, 256, 0, stream>>>(x_in, xbuf);
  transpose_w_r7<<<dim3(16, 16, 5), 256, 0, stream>>>(Ws, WT);
  repack_edges_r7<<<(2 * NE) / 256, 256, 0, stream>>>(ei, eidx);
  init_counts_r7<<<N_NODES / 256, 256, 0, stream>>>(counts);
  hist_dst_r7<<<NE / 256, 256, 0, stream>>>(eidx, counts);
  scan_kernel_r7<<<1, 1024, 0, stream>>>(counts, offs, cursor);
  scatter_edges_r7<<<ETOT / 256, 256, 0, stream>>>(eidx, cursor, csrc);

  for (int l = 0; l < NLAYERS; l++) {
    gemm_bt_r7<<<dim3(N_NODES / 128, DIM / 256), 512, 0, stream>>>(
        xbuf, WT + (size_t)l * DIM * DIM,
        Asrc + l * NH * DHEAD, Adst + l * NH * DHEAD, hbuf, als, ald);
    gat_agg_r7<<<AGG_BLOCKS, 256, 0, stream>>>(hbuf, als, ald, offs, csrc,
                                               Bconv + l * DIM, xbuf, ps, pq);
    bn_reduce_r7<<<512, 256, 0, stream>>>(ps, pq, Gamma + l * DIM, Beta + l * DIM, scale, shift);
    if (l < NLAYERS - 1)
      bn_apply_r7<<<(N_NODES * DIM / 8) / 256, 256, 0, stream>>>(xbuf, scale, shift);
  }
  final_head_r7<<<N_NODES / 4, 256, 0, stream>>>(xbuf, scale, shift, Wl, bl, out);
}